// Round 8
// baseline (94.702 us; speedup 1.0000x reference)
//
#include <hip/hip_runtime.h>
#include <cstddef>

#define Hn 1024
#define Vn 32000
#define Sn 4096
#define CSHIFT 20.0f

__device__ __forceinline__ float wave_reduce_sum(float v) {
#pragma unroll
    for (int o = 32; o > 0; o >>= 1) v += __shfl_down(v, o, 64);
    return v;
}

// ws layout (floats):
// [0,1024)        h
// [1024,2048)     raw ctx (unnormalized)
// [2048,3072)     v = attn_w^T h
// [3072,7168)     escore (e^(s-20), unnormalized)
// [7168]          denom
// [8192,8192+256*1024)  sctx partials

// out-head h-half: out[row] = out_w[row,0:1024].h + out_b[row]  (4 rows/block)
__device__ __forceinline__ void out_h_rows(const float* __restrict__ out_w,
                                           const float* __restrict__ out_b,
                                           const float* __restrict__ ws_h,
                                           float* __restrict__ out,
                                           int row_base, int t)
{
    __shared__ float c[Hn];
    ((float4*)c)[t] = ((const float4*)ws_h)[t];
    __syncthreads();
    const int wv = t >> 6, lane = t & 63;
    const int row = row_base + wv;
    const float* w = out_w + (size_t)row * (2 * Hn);
    float acc = 0.f;
#pragma unroll
    for (int k = 0; k < 4; ++k) {
        const int idx = k * 256 + lane * 4;
        const float4 w4 = *(const float4*)(w + idx);
        acc += w4.x * c[idx] + w4.y * c[idx + 1] + w4.z * c[idx + 2] + w4.w * c[idx + 3];
    }
    acc = wave_reduce_sum(acc);
    if (lane == 0) out[row] = acc + out_b[row];
}

// ---------------- K1: GRU cell -> h (1024 blocks, block per output) ----------------
__global__ __launch_bounds__(256) void k_gru(const int* __restrict__ word,
                                             const float* __restrict__ emb,
                                             const float* __restrict__ h0,
                                             const float* __restrict__ w_ih,
                                             const float* __restrict__ w_hh,
                                             const float* __restrict__ b_ih,
                                             const float* __restrict__ b_hh,
                                             float* __restrict__ ws_h,
                                             float* __restrict__ ws_denom,
                                             float* __restrict__ out_h)
{
    const int k = blockIdx.x;
    const int t = threadIdx.x;

    if (k == 0 && t == 0) ws_denom[0] = 0.f;   // zero atomic target each call

    const float* x = emb + (size_t)word[0] * Hn;
    const float4 xv = ((const float4*)x)[t];
    const float4 hv = ((const float4*)h0)[t];

    float acc[6];
    const float* rows[6] = {
        w_ih + (size_t)k * Hn, w_ih + (size_t)(k + Hn) * Hn, w_ih + (size_t)(k + 2 * Hn) * Hn,
        w_hh + (size_t)k * Hn, w_hh + (size_t)(k + Hn) * Hn, w_hh + (size_t)(k + 2 * Hn) * Hn
    };
#pragma unroll
    for (int g = 0; g < 6; ++g) {
        const float4 w = ((const float4*)rows[g])[t];
        const float4 vv = (g < 3) ? xv : hv;
        acc[g] = w.x * vv.x + w.y * vv.y + w.z * vv.z + w.w * vv.w;
    }

    __shared__ float red[6][4];
    const int wv = t >> 6, lane = t & 63;
#pragma unroll
    for (int g = 0; g < 6; ++g) {
        const float s = wave_reduce_sum(acc[g]);
        if (lane == 0) red[g][wv] = s;
    }
    __syncthreads();
    if (t == 0) {
        float g0 = red[0][0] + red[0][1] + red[0][2] + red[0][3] + b_ih[k];
        float g1 = red[1][0] + red[1][1] + red[1][2] + red[1][3] + b_ih[k + Hn];
        float g2 = red[2][0] + red[2][1] + red[2][2] + red[2][3] + b_ih[k + 2 * Hn];
        float g3 = red[3][0] + red[3][1] + red[3][2] + red[3][3] + b_hh[k];
        float g4 = red[4][0] + red[4][1] + red[4][2] + red[4][3] + b_hh[k + Hn];
        float g5 = red[5][0] + red[5][1] + red[5][2] + red[5][3] + b_hh[k + 2 * Hn];
        float r = 1.f / (1.f + expf(-(g0 + g3)));
        float z = 1.f / (1.f + expf(-(g1 + g4)));
        float n = tanhf(g2 + r * g5);
        float hk = (1.f - z) * n + z * h0[k];
        ws_h[k]  = hk;
        out_h[k] = hk;
    }
}

// ------- K2: attnv (blocks 0..63) ∥ out_h rows [0,10668) -------
__global__ __launch_bounds__(256) void k_a(const float* __restrict__ attn_w,
                                           const float* __restrict__ ws_h,
                                           float* __restrict__ v,
                                           const float* __restrict__ out_w,
                                           const float* __restrict__ out_b,
                                           float* __restrict__ out)
{
    const int t = threadIdx.x, bid = blockIdx.x;
    if (bid < 64) {
        const int tj = t >> 4, tk = t & 15;
        const int k = bid * 16 + tk;
        float acc = 0.f;
        for (int j = tj; j < Hn; j += 16)
            acc += attn_w[(size_t)j * Hn + k] * ws_h[j];
        __shared__ float p[16][17];
        p[tj][tk] = acc;
        __syncthreads();
        if (t < 16) {
            float s = 0.f;
#pragma unroll
            for (int j = 0; j < 16; ++j) s += p[j][t];
            v[bid * 16 + t] = s;
        }
    } else {
        out_h_rows(out_w, out_b, ws_h, out, (bid - 64) * 4, t);
    }
}

// ------- K3: fused scores+e^s+ctx-partials (blocks 0..255, 16 rows each)
//         ∥ out_h rows [10668,21336) -------
__global__ __launch_bounds__(256) void k_sctx(const float* __restrict__ enc,
                                              const float* __restrict__ ws_v,
                                              float* __restrict__ escore,
                                              float* __restrict__ part,
                                              float* __restrict__ denom,
                                              const float* __restrict__ ws_h,
                                              const float* __restrict__ out_w,
                                              const float* __restrict__ out_b,
                                              float* __restrict__ out)
{
    const int t = threadIdx.x, bid = blockIdx.x;
    if (bid < 256) {
        __shared__ float rows[16][Hn];   // 64 KB
        __shared__ float vsh[Hn];        // 4 KB
        __shared__ float es[16];
        const int wv = t >> 6, lane = t & 63;
        const int s0 = bid * 16;

        ((float4*)vsh)[t] = ((const float4*)ws_v)[t];
        const float* erow = enc + (size_t)s0 * Hn;
#pragma unroll
        for (int r = 0; r < 16; ++r)
            ((float4*)rows[r])[t] = ((const float4*)(erow + (size_t)r * Hn))[t];
        __syncthreads();

        // scores: wave wv handles rows wv*4 .. wv*4+3
#pragma unroll
        for (int q = 0; q < 4; ++q) {
            const int r = wv * 4 + q;
            float a = 0.f;
#pragma unroll
            for (int k = 0; k < 4; ++k) {
                const int idx = k * 256 + lane * 4;
                const float4 e = *(const float4*)&rows[r][idx];
                a += e.x * vsh[idx] + e.y * vsh[idx + 1] + e.z * vsh[idx + 2] + e.w * vsh[idx + 3];
            }
            a = wave_reduce_sum(a);
            if (lane == 0) {
                const float ev = expf(a - CSHIFT);
                es[r] = ev;
                escore[s0 + r] = ev;
            }
        }
        __syncthreads();
        if (t == 0) {
            float d = 0.f;
#pragma unroll
            for (int r = 0; r < 16; ++r) d += es[r];
            atomicAdd(denom, d);
        }
        // ctx partial: thread t owns cols 4t..4t+3
        float4 acc = make_float4(0.f, 0.f, 0.f, 0.f);
#pragma unroll
        for (int r = 0; r < 16; ++r) {
            const float a = es[r];
            const float4 e = ((const float4*)rows[r])[t];
            acc.x += a * e.x; acc.y += a * e.y; acc.z += a * e.z; acc.w += a * e.w;
        }
        ((float4*)(part + (size_t)bid * Hn))[t] = acc;
    } else {
        out_h_rows(out_w, out_b, ws_h, out, 10668 + (bid - 256) * 4, t);
    }
}

// ------- K4: reduce partials (blocks 0..3) + attn out (blocks 4..7)
//         ∥ out_h rows [21336,32000) -------
__global__ __launch_bounds__(256) void k_red(const float* __restrict__ part,
                                             float* __restrict__ ctx,
                                             const float* __restrict__ escore,
                                             const float* __restrict__ denom,
                                             float* __restrict__ out_attn,
                                             const float* __restrict__ ws_h,
                                             const float* __restrict__ out_w,
                                             const float* __restrict__ out_b,
                                             float* __restrict__ out)
{
    const int t = threadIdx.x, bid = blockIdx.x;
    if (bid < 4) {
        const int j = bid * 256 + t;
        float acc = 0.f;
        for (int pb = 0; pb < 256; ++pb)
            acc += part[(size_t)pb * Hn + j];
        ctx[j] = acc;                       // raw (unnormalized)
    } else if (bid < 8) {
        const float inv = 1.f / denom[0];
        const int s = (bid - 4) * 1024 + t * 4;
        const float4 e = *(const float4*)(escore + s);
        *(float4*)(out_attn + s) = make_float4(e.x * inv, e.y * inv, e.z * inv, e.w * inv);
    } else {
        out_h_rows(out_w, out_b, ws_h, out, 21336 + (bid - 8) * 4, t);
    }
}

// ------- K5: out[row] += (out_w[row,1024:2048] . rawctx) / denom -------
__global__ __launch_bounds__(256) void k_tail(const float* __restrict__ out_w,
                                              const float* __restrict__ ws_ctx,
                                              const float* __restrict__ denom,
                                              float* __restrict__ out)
{
    __shared__ float c[Hn];
    const int t = threadIdx.x;
    ((float4*)c)[t] = ((const float4*)ws_ctx)[t];
    __syncthreads();
    const int wv = t >> 6, lane = t & 63;
    const int row = blockIdx.x * 4 + wv;
    const float* w = out_w + (size_t)row * (2 * Hn) + Hn;
    float acc = 0.f;
#pragma unroll
    for (int k = 0; k < 4; ++k) {
        const int idx = k * 256 + lane * 4;
        const float4 w4 = *(const float4*)(w + idx);
        acc += w4.x * c[idx] + w4.y * c[idx + 1] + w4.z * c[idx + 2] + w4.w * c[idx + 3];
    }
    acc = wave_reduce_sum(acc);
    if (lane == 0) out[row] += acc * (1.f / denom[0]);
}

extern "C" void kernel_launch(void* const* d_in, const int* in_sizes, int n_in,
                              void* d_out, int out_size, void* d_ws, size_t ws_size,
                              hipStream_t stream) {
    const int*   word   = (const int*)d_in[0];
    const float* h_last = (const float*)d_in[1];
    const float* enc    = (const float*)d_in[2];
    const float* emb    = (const float*)d_in[3];
    const float* w_ih   = (const float*)d_in[4];
    const float* w_hh   = (const float*)d_in[5];
    const float* b_ih   = (const float*)d_in[6];
    const float* b_hh   = (const float*)d_in[7];
    const float* attn_w = (const float*)d_in[8];
    /* d_in[9] attn_b: unused — uniform shift, softmax-invariant */
    const float* out_w  = (const float*)d_in[10];
    const float* out_b  = (const float*)d_in[11];
    float* out = (float*)d_out;
    float* ws  = (float*)d_ws;

    float* ws_h      = ws;          // 1024
    float* ws_ctx    = ws + 1024;   // 1024 raw ctx
    float* ws_v      = ws + 2048;   // 1024
    float* ws_escore = ws + 3072;   // 4096
    float* ws_denom  = ws + 7168;   // 1
    float* ws_part   = ws + 8192;   // 256*1024
    float* out_h     = out + Vn;
    float* out_attn  = out + Vn + Hn;

    k_gru<<<Hn, 256, 0, stream>>>(word, emb, h_last, w_ih, w_hh, b_ih, b_hh, ws_h, ws_denom, out_h);
    k_a<<<64 + 2667, 256, 0, stream>>>(attn_w, ws_h, ws_v, out_w, out_b, out);
    k_sctx<<<256 + 2667, 256, 0, stream>>>(enc, ws_v, ws_escore, ws_part, ws_denom,
                                           ws_h, out_w, out_b, out);
    k_red<<<8 + 2666, 256, 0, stream>>>(ws_part, ws_ctx, ws_escore, ws_denom, out_attn,
                                        ws_h, out_w, out_b, out);
    k_tail<<<Vn / 4, 256, 0, stream>>>(out_w, ws_ctx, ws_denom, out);
}